// Round 3
// baseline (173.908 us; speedup 1.0000x reference)
//
#include <hip/hip_runtime.h>

#define NB 4
#define LQ 512
#define LK 512
#define EE 128
#define DD 256

__device__ __forceinline__ float fast_rcp(float x) { return __builtin_amdgcn_rcpf(x); }

// K1: rows 0..2047 = query@Wc1 -> Eq=exp(2q); rows 2048..4095 = key@Wc2 -> Ek=exp(2k)
// 16 rows per block (256 blocks), 256 threads (2 row-groups x 128 cols), 8 rows/thread.
// Eq/Ek live in the ctx region of d_out; K3 overwrites it after K2 consumed them.
__global__ __launch_bounds__(256) void proj_exp_kernel(
    const float* __restrict__ query, const float* __restrict__ key,
    const float* __restrict__ Wc1, const float* __restrict__ Wc2,
    float* __restrict__ Eq, float* __restrict__ Ek)
{
    __shared__ float in_s[16][DD];   // 16 KB
    const int r0 = blockIdx.x * 16;
    const float* src; const float* W; float* dst; int rbase;
    if (r0 < NB * LQ) { src = query; W = Wc1; dst = Eq; rbase = r0; }
    else              { src = key;   W = Wc2; dst = Ek; rbase = r0 - NB * LQ; }
    const float4* srow4 = (const float4*)(src + (size_t)rbase * DD);
    #pragma unroll
    for (int i = 0; i < 4; ++i)
        ((float4*)in_s)[i * 256 + threadIdx.x] = srow4[i * 256 + threadIdx.x];
    __syncthreads();
    const int c  = threadIdx.x & 127;
    const int rg = threadIdx.x >> 7;   // 0..1 -> rows rg*8 .. rg*8+7 (wave-uniform)
    float acc[8] = {0,0,0,0,0,0,0,0};
    for (int d = 0; d < DD; d += 4) {
        const float w0 = W[(d + 0) * EE + c];
        const float w1 = W[(d + 1) * EE + c];
        const float w2 = W[(d + 2) * EE + c];
        const float w3 = W[(d + 3) * EE + c];
        #pragma unroll
        for (int i = 0; i < 8; ++i) {
            const float4 x = *(const float4*)&in_s[rg * 8 + i][d];  // wave-uniform -> LDS broadcast
            acc[i] += x.x * w0 + x.y * w1 + x.z * w2 + x.w * w3;
        }
    }
    #pragma unroll
    for (int i = 0; i < 8; ++i)
        dst[(size_t)(rbase + rg * 8 + i) * EE + c] = __expf(2.0f * acc[i]);
}

// K2: block = (b, 4 l-rows). tanh(x) = 1 - 2/(e^{2x}+1): sjt = vcsum - 2*sum_e vc_e/(Eq*Ek+1).
// Eq staged through LDS in 4 chunks of 128 q-rows (coalesced global, padded rows).
// Each wave covers 32 rows x 2 e-halves; halves combined with one shfl_xor(32).
__global__ __launch_bounds__(256) void atten_kernel(
    const float* __restrict__ Eq, const float* __restrict__ Ek,
    const float* __restrict__ vc, float* __restrict__ attn)
{
    __shared__ float eq_s[128][132];   // 66 KB, +4 pad keeps 16B align, breaks bank stride
    __shared__ float sj_s[4][LQ];      // 8 KB
    __shared__ float rinv_s[4];
    const int b    = blockIdx.x >> 7;
    const int lt   = blockIdx.x & 127;
    const int l0   = lt * 4;
    const int tid  = threadIdx.x;
    const int w    = tid >> 6, lane = tid & 63;
    const int r_lo = lane & 31;        // row within wave's 32-row group
    const int h    = lane >> 5;        // e-half (0: e<64, 1: e>=64)
    const float* eqb = Eq + (size_t)b * LQ * EE;
    const float* ekb = Ek + ((size_t)b * LK + l0) * EE;

    float vcsum = 0.f;
    for (int e = 0; e < EE; e += 4) {
        const float4 v = *(const float4*)(vc + e);
        vcsum += (v.x + v.y) + (v.z + v.w);
    }

    for (int chunk = 0; chunk < 4; ++chunk) {
        const int q0 = chunk * 128;
        // coalesced coop load: 128 rows x 128 floats -> padded LDS
        #pragma unroll
        for (int i = 0; i < 16; ++i) {
            const int idx = i * 256 + tid;        // float4 index, 0..4095
            const int row = idx >> 5, c4 = idx & 31;
            *(float4*)&eq_s[row][c4 * 4] =
                *(const float4*)(eqb + (size_t)(q0 + row) * EE + c4 * 4);
        }
        __syncthreads();

        const int myr = w * 32 + r_lo;            // row in chunk
        const float* myrow = &eq_s[myr][h * 64];
        float s2[4] = {0.f, 0.f, 0.f, 0.f};
        #pragma unroll
        for (int e4 = 0; e4 < 16; ++e4) {
            const int e = h * 64 + e4 * 4;        // absolute e
            const float4 a  = *(const float4*)(myrow + e4 * 4);
            const float4 vv = *(const float4*)(vc + e);
            #pragma unroll
            for (int l = 0; l < 4; ++l) {
                const float4 kk = *(const float4*)(ekb + l * EE + e);
                s2[l] += vv.x * fast_rcp(a.x * kk.x + 1.0f);
                s2[l] += vv.y * fast_rcp(a.y * kk.y + 1.0f);
                s2[l] += vv.z * fast_rcp(a.z * kk.z + 1.0f);
                s2[l] += vv.w * fast_rcp(a.w * kk.w + 1.0f);
            }
        }
        #pragma unroll
        for (int l = 0; l < 4; ++l) {
            s2[l] += __shfl_xor(s2[l], 32);       // combine e-halves
            if (h == 0) sj_s[l][q0 + myr] = vcsum - 2.0f * s2[l];
        }
        __syncthreads();   // protects eq_s reuse; last one publishes sj_s for phase 2
    }

    // phase 2: softmax over q; wave w owns row l=w
    float m = -1e30f;
    #pragma unroll
    for (int i = 0; i < 8; ++i) m = fmaxf(m, sj_s[w][lane + 64 * i]);
    #pragma unroll
    for (int off = 32; off >= 1; off >>= 1) m = fmaxf(m, __shfl_xor(m, off));
    float Z = 0.f;
    #pragma unroll
    for (int i = 0; i < 8; ++i) {
        const float ex = __expf(sj_s[w][lane + 64 * i] - m);
        sj_s[w][lane + 64 * i] = ex;              // lane-exclusive slots
        Z += ex;
    }
    #pragma unroll
    for (int off = 32; off >= 1; off >>= 1) Z += __shfl_xor(Z, off);
    if (lane == 0) rinv_s[w] = fast_rcp(Z);
    __syncthreads();

    // phase 3: write atten (coalesced per l-row)
    #pragma unroll
    for (int qq = 0; qq < 2; ++qq) {
        const int q = tid + qq * 256;
        #pragma unroll
        for (int l = 0; l < 4; ++l)
            attn[(size_t)(b * LK + l0 + l) * LQ + q] = sj_s[l][q] * rinv_s[l];
    }
}

// K3: context[b,l,:] = sum_q atten[b,l,q] * value[b,q,:]
// block = (b, 8 l-rows) -> 256 blocks, halves value L2 traffic vs 4-row tiles.
// 4 q-groups x 64 d-threads (float4/thread); LDS reduce. Overwrites Eq/Ek region.
__global__ __launch_bounds__(256) void context_kernel(
    const float* __restrict__ attn, const float* __restrict__ value,
    float* __restrict__ ctx)
{
    const int b    = blockIdx.x >> 6;
    const int lt   = blockIdx.x & 63;
    const int row0 = b * LK + lt * 8;
    const int tid  = threadIdx.x;
    const int dth  = tid & 63;     // float4 chunk of d
    const int g    = tid >> 6;     // q-group
    const float4* v4 = (const float4*)(value + (size_t)b * LQ * DD);
    float ac[8][4];
    #pragma unroll
    for (int l = 0; l < 8; ++l) { ac[l][0]=0.f; ac[l][1]=0.f; ac[l][2]=0.f; ac[l][3]=0.f; }
    const int q0 = g * 128;
    for (int q = q0; q < q0 + 128; ++q) {
        const float4 v = v4[(size_t)q * 64 + dth];      // coalesced
        float al[8];
        #pragma unroll
        for (int l = 0; l < 8; ++l)
            al[l] = attn[(size_t)(row0 + l) * LQ + q];  // wave-uniform
        #pragma unroll
        for (int l = 0; l < 8; ++l) {
            ac[l][0] += al[l] * v.x; ac[l][1] += al[l] * v.y;
            ac[l][2] += al[l] * v.z; ac[l][3] += al[l] * v.w;
        }
    }
    __shared__ float red[4][8][64][4];   // 32 KiB
    #pragma unroll
    for (int l = 0; l < 8; ++l) {
        red[g][l][dth][0] = ac[l][0]; red[g][l][dth][1] = ac[l][1];
        red[g][l][dth][2] = ac[l][2]; red[g][l][dth][3] = ac[l][3];
    }
    __syncthreads();
    #pragma unroll
    for (int j = 0; j < 2; ++j) {
        const int l  = (tid >> 6) + j * 4;
        const int dt = tid & 63;
        float4 c;
        c.x = red[0][l][dt][0] + red[1][l][dt][0] + red[2][l][dt][0] + red[3][l][dt][0];
        c.y = red[0][l][dt][1] + red[1][l][dt][1] + red[2][l][dt][1] + red[3][l][dt][1];
        c.z = red[0][l][dt][2] + red[1][l][dt][2] + red[2][l][dt][2] + red[3][l][dt][2];
        c.w = red[0][l][dt][3] + red[1][l][dt][3] + red[2][l][dt][3] + red[3][l][dt][3];
        ((float4*)ctx)[(size_t)(row0 + l) * 64 + dt] = c;
    }
}

extern "C" void kernel_launch(void* const* d_in, const int* in_sizes, int n_in,
                              void* d_out, int out_size, void* d_ws, size_t ws_size,
                              hipStream_t stream) {
    const float* query = (const float*)d_in[0];
    const float* key   = (const float*)d_in[1];
    const float* value = (const float*)d_in[2];
    const float* Wc1   = (const float*)d_in[3];
    const float* Wc2   = (const float*)d_in[4];
    const float* vc    = (const float*)d_in[5];

    float* ctx  = (float*)d_out;                          // [B, Lk, D]   = 524288 floats
    float* attn = (float*)d_out + (size_t)NB * LK * DD;   // [B, Lk, Lq]  = 1048576 floats

    // Scratch lives inside d_out's ctx region (exactly 2*NB*LQ*EE = 524288 floats).
    // K1 writes Eq/Ek there; K2 reads them and writes attn (disjoint);
    // K3 then overwrites the ctx region with the final context. No d_ws use.
    float* Eq = ctx;                                      // [B, Lq, E] = 262144 floats
    float* Ek = ctx + (size_t)NB * LQ * EE;               // [B, Lk, E] = 262144 floats

    proj_exp_kernel<<<dim3(256), dim3(256), 0, stream>>>(query, key, Wc1, Wc2, Eq, Ek);
    atten_kernel<<<dim3(NB * (LK / 4)), dim3(256), 0, stream>>>(Eq, Ek, vc, attn);
    context_kernel<<<dim3(NB * (LK / 8)), dim3(256), 0, stream>>>(attn, value, ctx);
}

// Round 4
// 150.667 us; speedup vs baseline: 1.1543x; 1.1543x over previous
//
#include <hip/hip_runtime.h>

#define NB 4
#define LQ 512
#define LK 512
#define EE 128
#define DD 256

__device__ __forceinline__ float fast_rcp(float x) { return __builtin_amdgcn_rcpf(x); }

// K1: rows 0..2047 = query@Wc1 -> EqT[b][e][q] = exp(2q) TRANSPOSED;
//     rows 2048..4095 = key@Wc2 -> Ek[b][l][e] = exp(2k) row-major.
// 8 rows per block (512 blocks), 256 threads = 2 row-groups x 128 cols, 4 rows/thread.
// EqT/Ek live in the ctx region of d_out; K3 overwrites it after K2 consumed them.
__global__ __launch_bounds__(256) void proj_exp_kernel(
    const float* __restrict__ query, const float* __restrict__ key,
    const float* __restrict__ Wc1, const float* __restrict__ Wc2,
    float* __restrict__ EqT, float* __restrict__ Ek)
{
    __shared__ float in_s[8][DD];   // 8 KB
    const int r0 = blockIdx.x * 8;
    const bool is_q = (r0 < NB * LQ);
    const float* src = is_q ? query : key;
    const float* W   = is_q ? Wc1   : Wc2;
    const int rbase  = is_q ? r0    : r0 - NB * LQ;

    const float4* srow4 = (const float4*)(src + (size_t)rbase * DD);
    #pragma unroll
    for (int i = 0; i < 2; ++i)
        ((float4*)in_s)[i * 256 + threadIdx.x] = srow4[i * 256 + threadIdx.x];
    __syncthreads();

    const int c  = threadIdx.x & 127;
    const int rg = threadIdx.x >> 7;   // 0..1 -> rows rg*4 .. rg*4+3 (wave-uniform)
    float acc[4] = {0.f, 0.f, 0.f, 0.f};
    for (int d = 0; d < DD; d += 4) {
        const float w0 = W[(d + 0) * EE + c];
        const float w1 = W[(d + 1) * EE + c];
        const float w2 = W[(d + 2) * EE + c];
        const float w3 = W[(d + 3) * EE + c];
        #pragma unroll
        for (int i = 0; i < 4; ++i) {
            const float4 x = *(const float4*)&in_s[rg * 4 + i][d];  // wave-uniform -> broadcast
            acc[i] += x.x * w0 + x.y * w1 + x.z * w2 + x.w * w3;
        }
    }
    if (is_q) {
        // transposed store: thread holds 4 consecutive q for column e=c
        const int b    = rbase >> 9;
        const int qloc = (rbase & 511) + rg * 4;
        float4 o;
        o.x = __expf(2.0f * acc[0]); o.y = __expf(2.0f * acc[1]);
        o.z = __expf(2.0f * acc[2]); o.w = __expf(2.0f * acc[3]);
        *(float4*)&EqT[((size_t)(b * EE + c)) * LQ + qloc] = o;
    } else {
        #pragma unroll
        for (int i = 0; i < 4; ++i)
            Ek[(size_t)(rbase + rg * 4 + i) * EE + c] = __expf(2.0f * acc[i]);
    }
}

// K2: block = (b, 4 l-rows), 512 threads, thread owns q = tid.
// tanh(x) = 1 - 2/(e^{2x}+1): sjt = vcsum - 2*sum_e vc_e/(EqT*Ek+1).
// EqT loads coalesced (lane=q); Ek/vc loads block-uniform -> scalar cache.
// No barriers in the main loop; softmax split across 8 waves (4 l x 2 q-halves).
__global__ __launch_bounds__(512) void atten_kernel(
    const float* __restrict__ EqT, const float* __restrict__ Ek,
    const float* __restrict__ vc, float* __restrict__ attn)
{
    __shared__ float  sj_s[4][LQ];      // 8 KB
    __shared__ float2 mZ_s[4][2];
    __shared__ float  scale_s[4][2];
    const int b   = blockIdx.x >> 7;
    const int lt  = blockIdx.x & 127;
    const int l0  = lt * 4;
    const int tid = threadIdx.x;
    const int q   = tid;
    const float* eqc = EqT + (size_t)b * EE * LQ + q;          // column base; stride LQ per e
    const float* ekb = Ek  + ((size_t)b * LK + l0) * EE;

    float vcsum = 0.f;
    for (int e = 0; e < EE; e += 4) {
        const float4 v = *(const float4*)(vc + e);
        vcsum += (v.x + v.y) + (v.z + v.w);
    }

    float s2[4] = {0.f, 0.f, 0.f, 0.f};
    for (int e = 0; e < EE; e += 4) {
        const float a0 = eqc[(size_t)(e + 0) * LQ];            // coalesced
        const float a1 = eqc[(size_t)(e + 1) * LQ];
        const float a2 = eqc[(size_t)(e + 2) * LQ];
        const float a3 = eqc[(size_t)(e + 3) * LQ];
        const float4 vv = *(const float4*)(vc + e);            // uniform -> s_load
        #pragma unroll
        for (int l = 0; l < 4; ++l) {
            const float4 kk = *(const float4*)(ekb + l * EE + e);  // uniform -> s_load
            s2[l] += vv.x * fast_rcp(a0 * kk.x + 1.0f);
            s2[l] += vv.y * fast_rcp(a1 * kk.y + 1.0f);
            s2[l] += vv.z * fast_rcp(a2 * kk.z + 1.0f);
            s2[l] += vv.w * fast_rcp(a3 * kk.w + 1.0f);
        }
    }
    #pragma unroll
    for (int l = 0; l < 4; ++l)
        sj_s[l][q] = vcsum - 2.0f * s2[l];
    __syncthreads();

    // softmax over q: wave w handles (l = w&3, q-half h2 = w>>2)
    const int w = tid >> 6, lane = tid & 63;
    const int l = w & 3, h2 = w >> 2, base = h2 * 256;
    float m = -1e30f;
    #pragma unroll
    for (int i = 0; i < 4; ++i) m = fmaxf(m, sj_s[l][base + lane + 64 * i]);
    #pragma unroll
    for (int off = 32; off >= 1; off >>= 1) m = fmaxf(m, __shfl_xor(m, off));
    float Z = 0.f;
    #pragma unroll
    for (int i = 0; i < 4; ++i) {
        const int idx = base + lane + 64 * i;
        const float ex = __expf(sj_s[l][idx] - m);
        sj_s[l][idx] = ex;                                    // lane-exclusive
        Z += ex;
    }
    #pragma unroll
    for (int off = 32; off >= 1; off >>= 1) Z += __shfl_xor(Z, off);
    if (lane == 0) mZ_s[l][h2] = make_float2(m, Z);
    __syncthreads();
    if (lane == 0) {
        const float2 A = mZ_s[l][0], B2 = mZ_s[l][1];
        const float M  = fmaxf(A.x, B2.x);
        const float Zt = A.y * __expf(A.x - M) + B2.y * __expf(B2.x - M);
        scale_s[l][h2] = __expf((h2 ? B2.x : A.x) - M) * fast_rcp(Zt);
    }
    __syncthreads();

    #pragma unroll
    for (int li = 0; li < 4; ++li)
        attn[(size_t)(b * LK + l0 + li) * LQ + q] = sj_s[li][q] * scale_s[li][q >> 8];
}

// K3: context[b,l,:] = sum_q atten[b,l,q] * value[b,q,:]
// 256 blocks x 512 threads; wave w owns row lt*8+w; lanes own d-float4 (64x4=256=D).
// No LDS, no barriers; 8 waves/block share the value stream through L1.
// Overwrites the EqT/Ek region -- safe, K2 already consumed them (stream order).
__global__ __launch_bounds__(512) void context_kernel(
    const float* __restrict__ attn, const float* __restrict__ value,
    float* __restrict__ ctx)
{
    const int b    = blockIdx.x >> 6;
    const int lt   = blockIdx.x & 63;
    const int w    = threadIdx.x >> 6;
    const int lane = threadIdx.x & 63;
    const int row  = b * LK + lt * 8 + w;
    const float4* v4   = (const float4*)(value + (size_t)b * LQ * DD);
    const float*  arow = attn + (size_t)row * LQ;
    float4 ac = make_float4(0.f, 0.f, 0.f, 0.f);
    for (int q = 0; q < LQ; q += 4) {
        const float4 a4 = *(const float4*)(arow + q);          // broadcast (16B, all lanes same)
        const float4 v0 = v4[(size_t)(q + 0) * 64 + lane];     // coalesced
        const float4 v1 = v4[(size_t)(q + 1) * 64 + lane];
        const float4 v2 = v4[(size_t)(q + 2) * 64 + lane];
        const float4 v3 = v4[(size_t)(q + 3) * 64 + lane];
        ac.x += a4.x * v0.x; ac.y += a4.x * v0.y; ac.z += a4.x * v0.z; ac.w += a4.x * v0.w;
        ac.x += a4.y * v1.x; ac.y += a4.y * v1.y; ac.z += a4.y * v1.z; ac.w += a4.y * v1.w;
        ac.x += a4.z * v2.x; ac.y += a4.z * v2.y; ac.z += a4.z * v2.z; ac.w += a4.z * v2.w;
        ac.x += a4.w * v3.x; ac.y += a4.w * v3.y; ac.z += a4.w * v3.z; ac.w += a4.w * v3.w;
    }
    ((float4*)ctx)[(size_t)row * 64 + lane] = ac;
}

extern "C" void kernel_launch(void* const* d_in, const int* in_sizes, int n_in,
                              void* d_out, int out_size, void* d_ws, size_t ws_size,
                              hipStream_t stream) {
    const float* query = (const float*)d_in[0];
    const float* key   = (const float*)d_in[1];
    const float* value = (const float*)d_in[2];
    const float* Wc1   = (const float*)d_in[3];
    const float* Wc2   = (const float*)d_in[4];
    const float* vc    = (const float*)d_in[5];

    float* ctx  = (float*)d_out;                          // [B, Lk, D]   = 524288 floats
    float* attn = (float*)d_out + (size_t)NB * LK * DD;   // [B, Lk, Lq]  = 1048576 floats

    // Scratch lives inside d_out's ctx region (exactly 2*NB*LQ*EE = 524288 floats).
    // K1 writes EqT/Ek there; K2 reads them and writes attn (disjoint);
    // K3 then overwrites the ctx region with the final context. No d_ws use.
    float* EqT = ctx;                                     // [B, E, Lq] = 262144 floats
    float* Ek  = ctx + (size_t)NB * LQ * EE;              // [B, Lk, E] = 262144 floats

    proj_exp_kernel<<<dim3(512), dim3(256), 0, stream>>>(query, key, Wc1, Wc2, EqT, Ek);
    atten_kernel<<<dim3(NB * (LK / 4)), dim3(512), 0, stream>>>(EqT, Ek, vc, attn);
    context_kernel<<<dim3(NB * (LK / 8)), dim3(512), 0, stream>>>(attn, value, ctx);
}

// Round 5
// 124.658 us; speedup vs baseline: 1.3951x; 1.2086x over previous
//
#include <hip/hip_runtime.h>

#define NB 4
#define LQ 512
#define LK 512
#define EE 128
#define DD 256

__device__ __forceinline__ float fast_rcp(float x) { return __builtin_amdgcn_rcpf(x); }

// K1: rows 0..2047 = query@Wc1 -> EqT[b][e][q] = exp(2q) TRANSPOSED;
//     rows 2048..4095 = key@Wc2 -> Ek[b][l][e] = exp(2k) row-major.
// 8 rows per block (512 blocks), 256 threads = 2 row-groups x 128 cols, 4 rows/thread.
// EqT/Ek live in the ctx region of d_out; K3 overwrites it after K2 consumed them.
__global__ __launch_bounds__(256) void proj_exp_kernel(
    const float* __restrict__ query, const float* __restrict__ key,
    const float* __restrict__ Wc1, const float* __restrict__ Wc2,
    float* __restrict__ EqT, float* __restrict__ Ek)
{
    __shared__ float in_s[8][DD];   // 8 KB
    const int r0 = blockIdx.x * 8;
    const bool is_q = (r0 < NB * LQ);
    const float* src = is_q ? query : key;
    const float* W   = is_q ? Wc1   : Wc2;
    const int rbase  = is_q ? r0    : r0 - NB * LQ;

    const float4* srow4 = (const float4*)(src + (size_t)rbase * DD);
    #pragma unroll
    for (int i = 0; i < 2; ++i)
        ((float4*)in_s)[i * 256 + threadIdx.x] = srow4[i * 256 + threadIdx.x];
    __syncthreads();

    const int c  = threadIdx.x & 127;
    const int rg = threadIdx.x >> 7;   // 0..1 -> rows rg*4 .. rg*4+3 (wave-uniform)
    float acc[4] = {0.f, 0.f, 0.f, 0.f};
    for (int d = 0; d < DD; d += 4) {
        const float w0 = W[(d + 0) * EE + c];
        const float w1 = W[(d + 1) * EE + c];
        const float w2 = W[(d + 2) * EE + c];
        const float w3 = W[(d + 3) * EE + c];
        #pragma unroll
        for (int i = 0; i < 4; ++i) {
            const float4 x = *(const float4*)&in_s[rg * 4 + i][d];  // wave-uniform -> broadcast
            acc[i] += x.x * w0 + x.y * w1 + x.z * w2 + x.w * w3;
        }
    }
    if (is_q) {
        // transposed store: thread holds 4 consecutive q for column e=c
        const int b    = rbase >> 9;
        const int qloc = (rbase & 511) + rg * 4;
        float4 o;
        o.x = __expf(2.0f * acc[0]); o.y = __expf(2.0f * acc[1]);
        o.z = __expf(2.0f * acc[2]); o.w = __expf(2.0f * acc[3]);
        *(float4*)&EqT[((size_t)(b * EE + c)) * LQ + qloc] = o;
    } else {
        #pragma unroll
        for (int i = 0; i < 4; ++i)
            Ek[(size_t)(rbase + rg * 4 + i) * EE + c] = __expf(2.0f * acc[i]);
    }
}

// K2: block = (b, 4 l-rows), 512 threads, thread owns q = tid.
// tanh(x) = 1 - 2/(e^{2x}+1): sjt = vcsum - 2*sum_e vc_e/(EqT*Ek+1).
// EqT loads coalesced (lane=q); Ek/vc loads block-uniform -> broadcast.
// No barriers in the main loop; softmax split across 8 waves (4 l x 2 q-halves).
__global__ __launch_bounds__(512) void atten_kernel(
    const float* __restrict__ EqT, const float* __restrict__ Ek,
    const float* __restrict__ vc, float* __restrict__ attn)
{
    __shared__ float  sj_s[4][LQ];      // 8 KB
    __shared__ float2 mZ_s[4][2];
    __shared__ float  scale_s[4][2];
    const int b   = blockIdx.x >> 7;
    const int lt  = blockIdx.x & 127;
    const int l0  = lt * 4;
    const int tid = threadIdx.x;
    const int q   = tid;
    const float* eqc = EqT + (size_t)b * EE * LQ + q;          // column base; stride LQ per e
    const float* ekb = Ek  + ((size_t)b * LK + l0) * EE;

    float vcsum = 0.f;
    for (int e = 0; e < EE; e += 4) {
        const float4 v = *(const float4*)(vc + e);
        vcsum += (v.x + v.y) + (v.z + v.w);
    }

    float s2[4] = {0.f, 0.f, 0.f, 0.f};
    for (int e = 0; e < EE; e += 4) {
        const float a0 = eqc[(size_t)(e + 0) * LQ];            // coalesced
        const float a1 = eqc[(size_t)(e + 1) * LQ];
        const float a2 = eqc[(size_t)(e + 2) * LQ];
        const float a3 = eqc[(size_t)(e + 3) * LQ];
        const float4 vv = *(const float4*)(vc + e);            // uniform
        #pragma unroll
        for (int l = 0; l < 4; ++l) {
            const float4 kk = *(const float4*)(ekb + l * EE + e);  // uniform
            s2[l] += vv.x * fast_rcp(a0 * kk.x + 1.0f);
            s2[l] += vv.y * fast_rcp(a1 * kk.y + 1.0f);
            s2[l] += vv.z * fast_rcp(a2 * kk.z + 1.0f);
            s2[l] += vv.w * fast_rcp(a3 * kk.w + 1.0f);
        }
    }
    #pragma unroll
    for (int l = 0; l < 4; ++l)
        sj_s[l][q] = vcsum - 2.0f * s2[l];
    __syncthreads();

    // softmax over q: wave w handles (l = w&3, q-half h2 = w>>2)
    const int w = tid >> 6, lane = tid & 63;
    const int l = w & 3, h2 = w >> 2, base = h2 * 256;
    float m = -1e30f;
    #pragma unroll
    for (int i = 0; i < 4; ++i) m = fmaxf(m, sj_s[l][base + lane + 64 * i]);
    #pragma unroll
    for (int off = 32; off >= 1; off >>= 1) m = fmaxf(m, __shfl_xor(m, off));
    float Z = 0.f;
    #pragma unroll
    for (int i = 0; i < 4; ++i) {
        const int idx = base + lane + 64 * i;
        const float ex = __expf(sj_s[l][idx] - m);
        sj_s[l][idx] = ex;                                    // lane-exclusive
        Z += ex;
    }
    #pragma unroll
    for (int off = 32; off >= 1; off >>= 1) Z += __shfl_xor(Z, off);
    if (lane == 0) mZ_s[l][h2] = make_float2(m, Z);
    __syncthreads();
    if (lane == 0) {
        const float2 A = mZ_s[l][0], B2 = mZ_s[l][1];
        const float M  = fmaxf(A.x, B2.x);
        const float Zt = A.y * __expf(A.x - M) + B2.y * __expf(B2.x - M);
        scale_s[l][h2] = __expf((h2 ? B2.x : A.x) - M) * fast_rcp(Zt);
    }
    __syncthreads();

    #pragma unroll
    for (int li = 0; li < 4; ++li)
        attn[(size_t)(b * LK + l0 + li) * LQ + q] = sj_s[li][q] * scale_s[li][q >> 8];
}

// K3: context[b,l,:] = sum_q atten[b,l,q] * value[b,q,:]
// block = (b, 8 l-rows), 512 threads = 8 q-groups(g) x 64 d-lanes.
// Each value float4 load feeds 8 rows x 4 q = 32 FMAs (register reuse);
// each block reads value[b] exactly once -> 128 MB total L2 traffic.
// 3-stage LDS tree reduce over q-groups. Overwrites EqT/Ek region (safe: K2 done).
__global__ __launch_bounds__(512) void context_kernel(
    const float* __restrict__ attn, const float* __restrict__ value,
    float* __restrict__ ctx)
{
    const int b    = blockIdx.x >> 6;
    const int lt   = blockIdx.x & 63;
    const int row0 = b * LK + lt * 8;
    const int tid  = threadIdx.x;
    const int g    = tid >> 6;      // q-group 0..7 -> q in [g*64, g*64+64)
    const int lane = tid & 63;      // d float4 chunk
    const float4* v4 = (const float4*)(value + (size_t)b * LQ * DD);

    float4 ac[8];
    #pragma unroll
    for (int l = 0; l < 8; ++l) ac[l] = make_float4(0.f, 0.f, 0.f, 0.f);

    const int q0 = g * 64;
    for (int q = q0; q < q0 + 64; q += 4) {
        float4 a[8];
        #pragma unroll
        for (int l = 0; l < 8; ++l)
            a[l] = *(const float4*)(attn + (size_t)(row0 + l) * LQ + q);  // broadcast
        const float4 v0 = v4[(size_t)(q + 0) * 64 + lane];                // coalesced
        const float4 v1 = v4[(size_t)(q + 1) * 64 + lane];
        const float4 v2 = v4[(size_t)(q + 2) * 64 + lane];
        const float4 v3 = v4[(size_t)(q + 3) * 64 + lane];
        #pragma unroll
        for (int l = 0; l < 8; ++l) {
            ac[l].x += a[l].x * v0.x; ac[l].y += a[l].x * v0.y;
            ac[l].z += a[l].x * v0.z; ac[l].w += a[l].x * v0.w;
            ac[l].x += a[l].y * v1.x; ac[l].y += a[l].y * v1.y;
            ac[l].z += a[l].y * v1.z; ac[l].w += a[l].y * v1.w;
            ac[l].x += a[l].z * v2.x; ac[l].y += a[l].z * v2.y;
            ac[l].z += a[l].z * v2.z; ac[l].w += a[l].z * v2.w;
            ac[l].x += a[l].w * v3.x; ac[l].y += a[l].w * v3.y;
            ac[l].z += a[l].w * v3.z; ac[l].w += a[l].w * v3.w;
        }
    }

    // tree reduce over the 8 q-groups: 8 -> 4 -> 2 -> 1
    __shared__ float4 red[4][8][64];   // 32 KB
    if (g >= 4) {
        #pragma unroll
        for (int l = 0; l < 8; ++l) red[g - 4][l][lane] = ac[l];
    }
    __syncthreads();
    if (g < 4) {
        #pragma unroll
        for (int l = 0; l < 8; ++l) {
            const float4 r = red[g][l][lane];
            ac[l].x += r.x; ac[l].y += r.y; ac[l].z += r.z; ac[l].w += r.w;
        }
    }
    __syncthreads();
    if (g == 2 || g == 3) {
        #pragma unroll
        for (int l = 0; l < 8; ++l) red[g - 2][l][lane] = ac[l];
    }
    __syncthreads();
    if (g < 2) {
        #pragma unroll
        for (int l = 0; l < 8; ++l) {
            const float4 r = red[g][l][lane];
            ac[l].x += r.x; ac[l].y += r.y; ac[l].z += r.z; ac[l].w += r.w;
        }
    }
    __syncthreads();
    if (g == 1) {
        #pragma unroll
        for (int l = 0; l < 8; ++l) red[0][l][lane] = ac[l];
    }
    __syncthreads();
    if (g == 0) {
        #pragma unroll
        for (int l = 0; l < 8; ++l) {
            const float4 r = red[0][l][lane];
            ac[l].x += r.x; ac[l].y += r.y; ac[l].z += r.z; ac[l].w += r.w;
            ((float4*)ctx)[(size_t)(row0 + l) * 64 + lane] = ac[l];
        }
    }
}

extern "C" void kernel_launch(void* const* d_in, const int* in_sizes, int n_in,
                              void* d_out, int out_size, void* d_ws, size_t ws_size,
                              hipStream_t stream) {
    const float* query = (const float*)d_in[0];
    const float* key   = (const float*)d_in[1];
    const float* value = (const float*)d_in[2];
    const float* Wc1   = (const float*)d_in[3];
    const float* Wc2   = (const float*)d_in[4];
    const float* vc    = (const float*)d_in[5];

    float* ctx  = (float*)d_out;                          // [B, Lk, D]   = 524288 floats
    float* attn = (float*)d_out + (size_t)NB * LK * DD;   // [B, Lk, Lq]  = 1048576 floats

    // Scratch lives inside d_out's ctx region (exactly 2*NB*LQ*EE = 524288 floats).
    // K1 writes EqT/Ek there; K2 reads them and writes attn (disjoint);
    // K3 then overwrites the ctx region with the final context. No d_ws use.
    float* EqT = ctx;                                     // [B, E, Lq] = 262144 floats
    float* Ek  = ctx + (size_t)NB * LQ * EE;              // [B, Lk, E] = 262144 floats

    proj_exp_kernel<<<dim3(512), dim3(256), 0, stream>>>(query, key, Wc1, Wc2, EqT, Ek);
    atten_kernel<<<dim3(NB * (LK / 4)), dim3(512), 0, stream>>>(EqT, Ek, vc, attn);
    context_kernel<<<dim3(NB * (LK / 8)), dim3(512), 0, stream>>>(attn, value, ctx);
}